// Round 9
// baseline (193577.405 us; speedup 1.0000x reference)
//
#include <hip/hip_runtime.h>
#include <math.h>

#define SEQ   8192
#define NIN   256
#define H     2048
#define NBLK  256
#define NTHR  256

typedef unsigned long long u64;

// ---- ws layout: u64 recs[2][NBLK][8] (32 KB) ----
// Element e of record (slot,b) = { hi32: step tag, lo32: f32 bits of h[8b+e] }.
// Self-validating: each 8B word carries its own epoch — no tag array, no
// ordering waits. Harness poison 0xAAAAAAAA can never equal a tag in
// [0,8192], so only slot 0 (h0, tag 0) needs init.
__global__ void lstm_init(const float* __restrict__ h0, u64* __restrict__ recs)
{
    const int j = threadIdx.x;   // one block of 256: record j of slot 0
    #pragma unroll
    for (int e = 0; e < 8; ++e)
        recs[8 * j + e] = (u64)__builtin_bit_cast(unsigned, h0[8 * j + e]);
}

// One 64B record line via 4 x 16B agent-scope (sc1) loads, then drain.
__device__ __forceinline__ void load_rec_sc1(const unsigned* p,
                                             uint4& a, uint4& b,
                                             uint4& c, uint4& d)
{
    asm volatile(
        "global_load_dwordx4 %0, %4, off sc1\n\t"
        "global_load_dwordx4 %1, %5, off sc1\n\t"
        "global_load_dwordx4 %2, %6, off sc1\n\t"
        "global_load_dwordx4 %3, %7, off sc1\n\t"
        "s_waitcnt vmcnt(0)"
        : "=&v"(a), "=&v"(b), "=&v"(c), "=&v"(d)
        : "v"(p), "v"(p + 4), "v"(p + 8), "v"(p + 12)
        : "memory");
}

// Persistent LSTM. fp32 weights register-resident, fp64 recurrence math,
// fp32 h transport via self-validating epoch-tagged u64 records.
// Block b owns h[8b..8b+8); wave wv computes gate wv; lane ln holds
// w_hh[R][32ln..32ln+32) for its 8 rows.
__global__ void __launch_bounds__(NTHR, 1)
lstm_persist(const float* __restrict__ x, const float* __restrict__ c0,
             const float* __restrict__ w_ih, const float* __restrict__ w_hh,
             const float* __restrict__ b_ih, const float* __restrict__ b_hh,
             const float* __restrict__ w_lin, const float* __restrict__ b_lin,
             float* __restrict__ out, u64* __restrict__ recs)
{
    const int b = blockIdx.x, tid = threadIdx.x;
    const int wv = tid >> 6, ln = tid & 63;

    __shared__ float  h_lds[H + H / 32];   // stride-33: 2-way bank alias = free
    __shared__ double gsum[4][8];
    __shared__ double bias_s[4][8];
    __shared__ double red0[4], red1[4];

    if (tid < 32) {
        int g = tid >> 3, r = tid & 7;
        int R = g * H + b * 8 + r;
        bias_s[g][r] = (double)b_ih[R] + (double)b_hh[R];
    }
    double c_reg = (wv == 0 && ln < 8) ? (double)c0[b * 8 + ln] : 0.0;

    float wreg[8][32];
    float wih[8][4];
    #pragma unroll
    for (int r = 0; r < 8; ++r) {
        const int R = wv * H + b * 8 + r;
        const float4* wp = (const float4*)(w_hh + (size_t)R * H + ln * 32);
        #pragma unroll
        for (int q = 0; q < 8; ++q) ((float4*)wreg[r])[q] = wp[q];
        *(float4*)wih[r] = *(const float4*)(w_ih + (size_t)R * NIN + ln * 4);
    }
    __syncthreads();

    float4 xr = *(const float4*)(x + ln * 4);
    float4 xn = xr;

    for (int t = 0; t < SEQ; ++t) {
        // ---- consume-is-the-poll: retry own record line until tags == t ----
        {
            const unsigned* rp =
                (const unsigned*)(recs + (((size_t)(t & 1) * NBLK + tid) << 3));
            uint4 va, vb, vc, vd;
            const unsigned want = (unsigned)t;
            for (;;) {
                load_rec_sc1(rp, va, vb, vc, vd);
                bool ok = (va.y == want) & (va.w == want)
                        & (vb.y == want) & (vb.w == want)
                        & (vc.y == want) & (vc.w == want)
                        & (vd.y == want) & (vd.w == want);
                if (ok) break;
                __builtin_amdgcn_s_sleep(4);
            }
            const int base = 8 * tid + (tid >> 2);   // pad +1 per 32 floats
            h_lds[base + 0] = __builtin_bit_cast(float, va.x);
            h_lds[base + 1] = __builtin_bit_cast(float, va.z);
            h_lds[base + 2] = __builtin_bit_cast(float, vb.x);
            h_lds[base + 3] = __builtin_bit_cast(float, vb.z);
            h_lds[base + 4] = __builtin_bit_cast(float, vc.x);
            h_lds[base + 5] = __builtin_bit_cast(float, vc.z);
            h_lds[base + 6] = __builtin_bit_cast(float, vd.x);
            h_lds[base + 7] = __builtin_bit_cast(float, vd.z);
        }
        __syncthreads();   // A: full h of step t in LDS

        if (t + 1 < SEQ) xn = *(const float4*)(x + (size_t)(t + 1) * NIN + ln * 4);

        // ---- matvec: fp32 w x fp32 h, fp64 accumulate ----
        float hbuf[32];
        {
            const float* hp = &h_lds[33 * ln];
            #pragma unroll
            for (int q = 0; q < 32; ++q) hbuf[q] = hp[q];
        }
        double acc[8];
        #pragma unroll
        for (int r = 0; r < 8; ++r)
            acc[r] = (double)wih[r][0] * (double)xr.x + (double)wih[r][1] * (double)xr.y
                   + (double)wih[r][2] * (double)xr.z + (double)wih[r][3] * (double)xr.w;
        #pragma unroll
        for (int q = 0; q < 32; ++q) {
            const double hq = (double)hbuf[q];
            #pragma unroll
            for (int r = 0; r < 8; ++r)
                acc[r] = fma((double)wreg[r][q], hq, acc[r]);
        }
        #pragma unroll
        for (int off = 32; off >= 1; off >>= 1) {
            #pragma unroll
            for (int r = 0; r < 8; ++r) acc[r] += __shfl_xor(acc[r], off, 64);
        }
        if (ln == 0) {
            #pragma unroll
            for (int r = 0; r < 8; ++r) gsum[wv][r] = acc[r];
        }
        __syncthreads();   // B: gsum complete; everyone done reading h_lds

        // ---- wave 0: activations, state update, fire-and-forget publish ----
        // (waves 1-3 proceed straight into step t+1's consume-poll)
        if (wv == 0) {
            double actv = 0.0;
            if (ln < 32) {
                const int g = ln >> 3, j = ln & 7;
                double v = gsum[g][j] + bias_s[g][j];
                actv = (g == 2) ? tanh(v) : 1.0 / (1.0 + exp(-v));
            }
            const int j = ln & 7;
            double ai = __shfl(actv, j,      64);
            double af = __shfl(actv, j + 8,  64);
            double ag = __shfl(actv, j + 16, 64);
            double ao = __shfl(actv, j + 24, 64);
            if (ln < 8) {
                double c = af * c_reg + ai * ag;
                c_reg = c;
                float hnew = (float)(ao * tanh(c));
                u64 pv = ((u64)(unsigned)(t + 1) << 32)
                       | (u64)__builtin_bit_cast(unsigned, hnew);
                u64* dst = recs + (((size_t)((t + 1) & 1) * NBLK + b) << 3) + ln;
                __hip_atomic_store(dst, pv, __ATOMIC_RELAXED,
                                   __HIP_MEMORY_SCOPE_AGENT);
            }
        }
        xr = xn;
    }

    // ---- epilogue: block 0 gathers h(SEQ) (slot 0, tag SEQ) ----
    if (b == 0) {
        const unsigned* rp = (const unsigned*)(recs + ((size_t)tid << 3));
        uint4 va, vb, vc, vd;
        const unsigned want = (unsigned)SEQ;
        for (;;) {
            load_rec_sc1(rp, va, vb, vc, vd);
            bool ok = (va.y == want) & (va.w == want)
                    & (vb.y == want) & (vb.w == want)
                    & (vc.y == want) & (vc.w == want)
                    & (vd.y == want) & (vd.w == want);
            if (ok) break;
            __builtin_amdgcn_s_sleep(4);
        }
        double hv[8];
        hv[0] = (double)__builtin_bit_cast(float, va.x);
        hv[1] = (double)__builtin_bit_cast(float, va.z);
        hv[2] = (double)__builtin_bit_cast(float, vb.x);
        hv[3] = (double)__builtin_bit_cast(float, vb.z);
        hv[4] = (double)__builtin_bit_cast(float, vc.x);
        hv[5] = (double)__builtin_bit_cast(float, vc.z);
        hv[6] = (double)__builtin_bit_cast(float, vd.x);
        hv[7] = (double)__builtin_bit_cast(float, vd.z);
        double a0 = 0., a1 = 0.;
        #pragma unroll
        for (int e = 0; e < 8; ++e) {
            a0 = fma((double)w_lin[8 * tid + e],     hv[e], a0);
            a1 = fma((double)w_lin[H + 8 * tid + e], hv[e], a1);
        }
        #pragma unroll
        for (int off = 32; off >= 1; off >>= 1) {
            a0 += __shfl_xor(a0, off, 64);
            a1 += __shfl_xor(a1, off, 64);
        }
        if (ln == 0) { red0[wv] = a0; red1[wv] = a1; }
        __syncthreads();
        if (tid == 0) {
            out[0] = (float)(red0[0] + red0[1] + red0[2] + red0[3] + (double)b_lin[0]);
            out[1] = (float)(red1[0] + red1[1] + red1[2] + red1[3] + (double)b_lin[1]);
        }
    }
}

extern "C" void kernel_launch(void* const* d_in, const int* in_sizes, int n_in,
                              void* d_out, int out_size, void* d_ws, size_t ws_size,
                              hipStream_t stream) {
    const float* x     = (const float*)d_in[0];
    const float* h0    = (const float*)d_in[1];
    const float* c0    = (const float*)d_in[2];
    const float* w_ih  = (const float*)d_in[3];
    const float* w_hh  = (const float*)d_in[4];
    const float* b_ih  = (const float*)d_in[5];
    const float* b_hh  = (const float*)d_in[6];
    const float* w_lin = (const float*)d_in[7];
    const float* b_lin = (const float*)d_in[8];
    float* out  = (float*)d_out;
    u64*   recs = (u64*)d_ws;

    lstm_init<<<1, NTHR, 0, stream>>>(h0, recs);
    lstm_persist<<<NBLK, NTHR, 0, stream>>>(
        x, c0, w_ih, w_hh, b_ih, b_hh, w_lin, b_lin, out, recs);
}